// Round 19
// baseline (338.053 us; speedup 1.0000x reference)
//
#include <hip/hip_runtime.h>

#define B 8
#define N 1024
#define M 128
#define KF 16
#define C 16
#define DPE 64
#define NE 131072
#define NV (B*N)
#define NM (N*M)
#define BN_EPS 1e-5f

typedef short bf16x8 __attribute__((ext_vector_type(8)));
typedef float f32x4 __attribute__((ext_vector_type(4)));

__device__ inline unsigned short f2bf_rne(float f) {
    unsigned u = __float_as_uint(f);
    u += 0x7fffu + ((u >> 16) & 1u);
    return (unsigned short)(u >> 16);
}
__device__ inline float bf2f(unsigned short s) {
    return __uint_as_float((unsigned)s << 16);
}
__device__ inline void split_bf16(float v, unsigned short& hi, unsigned short& lo) {
    hi = f2bf_rne(v);
    float hf = __uint_as_float((unsigned)hi << 16);
    lo = f2bf_rne(v - hf);
}
union U4 { uint4 v; unsigned short s[8]; };
union U2 { uint2 v; unsigned short s[4]; };

// Sf frag-major (uint4 units): SF4(b,nsub,ks,hl,l) ; el = S[n=16nsub+(l&15)][k=32ks+8(l>>4)+j]
__device__ __host__ inline size_t SF4(int b, int nsub, int ks, int hl, int l) {
    return ((((size_t)b * 64 + nsub) * 32 + ks) * 2 + hl) * 64 + l;
}
// Pf frag-major (uint4 units) per buffer: PF4(b,msub,ks,hl,l)
__device__ __host__ inline size_t PF4(int b, int msub, int ks, int hl, int l) {
    return ((((size_t)b * 8 + msub) * 32 + ks) * 2 + hl) * 64 + l;
}
#define PFBUF ((size_t)B * 8 * 32 * 2 * 64)   // uint4 per Pf buffer (4MB)

// ---------- fused prep: S-frags | W plane0 (bf16, [node][m]) | W-frags ----------
// Block ranges (bases multiple of 8 -> blk&7 XCD pinning kept):
// [0,512) prep_s; [512,1536) plane0 cast-copy; [1536,2048) prep_w_frag.
__global__ __launch_bounds__(256) void prep_all(const float* __restrict__ Lap,
                                                const float* __restrict__ W,
                                                uint4* __restrict__ Sf,
                                                uint4* __restrict__ Pf,
                                                unsigned short* __restrict__ feat) {
    int blk = blockIdx.x;
    int t = threadIdx.x;
    if (blk < 512) {                          // ---- prep_s ----
        int b = blk & 7, nb = blk >> 3;
        int nl = t >> 4, kg = t & 15;
        int n = nb * 16 + nl;
        const float* row = Lap + ((size_t)b * N + n) * N;
        #pragma unroll
        for (int jj = 0; jj < 8; jj++) {
            int koct = kg + 16 * jj;
            int k0 = koct * 8;
            float4 f0 = *(const float4*)(row + k0);
            float4 f1 = *(const float4*)(row + k0 + 4);
            float e[8] = {f0.x, f0.y, f0.z, f0.w, f1.x, f1.y, f1.z, f1.w};
            U4 hi, lo;
            #pragma unroll
            for (int j = 0; j < 8; j++) split_bf16(e[j], hi.s[j], lo.s[j]);
            int ks = k0 >> 5;
            int lf = nl + 16 * (koct & 3);
            Sf[SF4(b, nb, ks, 0, lf)] = hi.v;
            Sf[SF4(b, nb, ks, 1, lf)] = lo.v;
        }
    } else if (blk < 1536) {                  // ---- plane 0: W cast to bf16 ([n][m] already) ----
        int r = blk - 512;
        int b = r & 7;
        int idx = (r >> 3) * 256 + t;         // quad index 0..32767 per batch
        float4 v = *(const float4*)(W + (size_t)b * NM + (size_t)idx * 4);
        U2 o;
        o.s[0] = f2bf_rne(v.x); o.s[1] = f2bf_rne(v.y);
        o.s[2] = f2bf_rne(v.z); o.s[3] = f2bf_rne(v.w);
        *(uint2*)(feat + (size_t)b * KF * NM + (size_t)idx * 4) = o.v;
    } else {                                  // ---- prep_w_frag ----
        int r0 = blk - 1536;
        int b = r0 & 7;
        int r = (r0 >> 3) * 256 + t;
        int msub = r >> 11, ks = (r >> 6) & 31, l = r & 63;
        int m = 16 * msub + (l & 15);
        U4 hi, lo;
        #pragma unroll
        for (int j = 0; j < 8; j++) {
            int n = 32 * ks + 8 * (l >> 4) + j;
            float v = W[((size_t)b * N + n) * M + m];
            split_bf16(v, hi.s[j], lo.s[j]);
        }
        Pf[PF4(b, msub, ks, 0, l)] = hi.v;
        Pf[PF4(b, msub, ks, 1, l)] = lo.v;
    }
}

// ---------- persistent MFMA chain, Sf LDS-resident, bf16 [node][m] planes ----------
__global__ __launch_bounds__(512) void gemm_chain(const uint4* __restrict__ Sf,
                                                  uint4* __restrict__ PfA,
                                                  uint4* __restrict__ PfB,
                                                  unsigned short* __restrict__ feat,
                                                  unsigned* bar) {
    extern __shared__ __align__(16) char smem[];
    uint4* ldsS = (uint4*)smem;               // 8192 uint4 = 128 KB
    float* Dl = (float*)(smem + 131072);      // 128 x 36 floats = 18.4 KB

    int b = blockIdx.x & 7, bx = blockIdx.x >> 3;   // XCD pinning
    int t = threadIdx.x;
    int w = t >> 6, lane = t & 63;
    int g = w >> 2, wq = w & 3;               // K-half, msub-pair
    size_t sbase = SF4(b, 2 * bx, 0, 0, 0);
    int n0 = 32 * bx;

    #pragma unroll
    for (int i = 0; i < 16; i++) ldsS[t + 512 * i] = Sf[sbase + t + 512 * i];
    __syncthreads();

    #pragma unroll 1
    for (int k = 0; k < KF - 1; k++) {
        const uint4* PfIn = (k & 1) ? PfB : PfA;
        uint4* PfOut      = (k & 1) ? PfA : PfB;
        const uint4* Pw0 = PfIn + (size_t)(b * 8 + 2 * wq) * 4096 + (size_t)(16 * g) * 128;
        const uint4* Pw1 = Pw0 + 4096;

        f32x4 acc[2][2] = {};
        uint4 ph[2][2], pl[2][2];
        #pragma unroll
        for (int q = 0; q < 2; q++) {
            ph[q][0] = Pw0[(size_t)q * 128 + lane];
            pl[q][0] = Pw0[(size_t)q * 128 + 64 + lane];
            ph[q][1] = Pw1[(size_t)q * 128 + lane];
            pl[q][1] = Pw1[(size_t)q * 128 + 64 + lane];
        }
        #pragma unroll 2
        for (int ks = 0; ks < 16; ks++) {
            int kg = 16 * g + ks;
            uint4 a0h = ph[ks & 1][0], a0l = pl[ks & 1][0];
            uint4 a1h = ph[ks & 1][1], a1l = pl[ks & 1][1];
            if (ks < 14) {
                ph[ks & 1][0] = Pw0[(size_t)(ks + 2) * 128 + lane];
                pl[ks & 1][0] = Pw0[(size_t)(ks + 2) * 128 + 64 + lane];
                ph[ks & 1][1] = Pw1[(size_t)(ks + 2) * 128 + lane];
                pl[ks & 1][1] = Pw1[(size_t)(ks + 2) * 128 + 64 + lane];
            }
            bf16x8 b0h = __builtin_bit_cast(bf16x8, ldsS[kg * 128 + lane]);
            bf16x8 b0l = __builtin_bit_cast(bf16x8, ldsS[kg * 128 + 64 + lane]);
            bf16x8 b1h = __builtin_bit_cast(bf16x8, ldsS[4096 + kg * 128 + lane]);
            bf16x8 b1l = __builtin_bit_cast(bf16x8, ldsS[4096 + kg * 128 + 64 + lane]);
            bf16x8 A0h = __builtin_bit_cast(bf16x8, a0h);
            bf16x8 A0l = __builtin_bit_cast(bf16x8, a0l);
            bf16x8 A1h = __builtin_bit_cast(bf16x8, a1h);
            bf16x8 A1l = __builtin_bit_cast(bf16x8, a1l);
            acc[0][0] = __builtin_amdgcn_mfma_f32_16x16x32_bf16(A0h, b0h, acc[0][0], 0, 0, 0);
            acc[0][0] = __builtin_amdgcn_mfma_f32_16x16x32_bf16(A0h, b0l, acc[0][0], 0, 0, 0);
            acc[0][0] = __builtin_amdgcn_mfma_f32_16x16x32_bf16(A0l, b0h, acc[0][0], 0, 0, 0);
            acc[0][1] = __builtin_amdgcn_mfma_f32_16x16x32_bf16(A0h, b1h, acc[0][1], 0, 0, 0);
            acc[0][1] = __builtin_amdgcn_mfma_f32_16x16x32_bf16(A0h, b1l, acc[0][1], 0, 0, 0);
            acc[0][1] = __builtin_amdgcn_mfma_f32_16x16x32_bf16(A0l, b1h, acc[0][1], 0, 0, 0);
            acc[1][0] = __builtin_amdgcn_mfma_f32_16x16x32_bf16(A1h, b0h, acc[1][0], 0, 0, 0);
            acc[1][0] = __builtin_amdgcn_mfma_f32_16x16x32_bf16(A1h, b0l, acc[1][0], 0, 0, 0);
            acc[1][0] = __builtin_amdgcn_mfma_f32_16x16x32_bf16(A1l, b0h, acc[1][0], 0, 0, 0);
            acc[1][1] = __builtin_amdgcn_mfma_f32_16x16x32_bf16(A1h, b1h, acc[1][1], 0, 0, 0);
            acc[1][1] = __builtin_amdgcn_mfma_f32_16x16x32_bf16(A1h, b1l, acc[1][1], 0, 0, 0);
            acc[1][1] = __builtin_amdgcn_mfma_f32_16x16x32_bf16(A1l, b1h, acc[1][1], 0, 0, 0);
        }

        // ---- K-half reduction through Dl: g=1 writes, g=0 adds ----
        if (g == 1) {
            #pragma unroll
            for (int mi = 0; mi < 2; mi++)
                #pragma unroll
                for (int ni = 0; ni < 2; ni++)
                    #pragma unroll
                    for (int r = 0; r < 4; r++) {
                        int m = 32 * wq + 16 * mi + 4 * (lane >> 4) + r;
                        int c = 16 * ni + (lane & 15);
                        Dl[m * 36 + c] = acc[mi][ni][r];
                    }
        }
        __syncthreads();
        if (g == 0) {
            #pragma unroll
            for (int mi = 0; mi < 2; mi++)
                #pragma unroll
                for (int ni = 0; ni < 2; ni++)
                    #pragma unroll
                    for (int r = 0; r < 4; r++) {
                        int m = 32 * wq + 16 * mi + 4 * (lane >> 4) + r;
                        int c = 16 * ni + (lane & 15);
                        Dl[m * 36 + c] += acc[mi][ni][r];
                    }
        }
        __syncthreads();
        {   // bf16 plane write ([node][m]); n=t&31 (conflict-free LDS), m0=(t>>5)*8
            int n = t & 31, m0 = (t >> 5) * 8;
            U4 o;
            #pragma unroll
            for (int j = 0; j < 8; j++) o.s[j] = f2bf_rne(Dl[(m0 + j) * 36 + n]);
            unsigned short* plane = feat + ((size_t)b * KF + (k + 1)) * NM + (size_t)(n0 + n) * M + m0;
            *(uint4*)plane = o.v;
        }
        if (k < KF - 2) {
            {   // next-step A frags (hi/lo), ks = bx; msub = w
                int l = t & 63;
                int m = 16 * w + (l & 15);
                int ncol = 8 * (l >> 4);
                float4 v0 = *(const float4*)&Dl[m * 36 + ncol];
                float4 v1 = *(const float4*)&Dl[m * 36 + ncol + 4];
                float e[8] = {v0.x, v0.y, v0.z, v0.w, v1.x, v1.y, v1.z, v1.w};
                U4 hi, lo;
                #pragma unroll
                for (int j = 0; j < 8; j++) split_bf16(e[j], hi.s[j], lo.s[j]);
                PfOut[PF4(b, w, bx, 0, l)] = hi.v;
                PfOut[PF4(b, w, bx, 1, l)] = lo.v;
            }
            __syncthreads();   // drains Pf stores to L2 (vmcnt(0))
            if (t == 0) {
                __hip_atomic_fetch_add(&bar[b * 32], 1u, __ATOMIC_RELAXED,
                                       __HIP_MEMORY_SCOPE_AGENT);
                unsigned target = 32u * (unsigned)(k + 1);
                while (__hip_atomic_load(&bar[b * 32], __ATOMIC_RELAXED,
                                         __HIP_MEMORY_SCOPE_AGENT) < target)
                    __builtin_amdgcn_s_sleep(1);
            }
            __syncthreads();
            asm volatile("buffer_inv sc0\n\ts_waitcnt vmcnt(0)" ::: "memory");
        } else {
            __syncthreads();
        }
    }
}

// ---------- fused BN: stats -> per-batch barrier -> apply+relu+mean -> x ----------
// grid 256 (1 block/CU, co-residency guaranteed), b=blk&7 XCD-pinned.
// Phase 2 re-reads the batch's 4MB plane set L2-warm. feat is [node][m] bf16.
__global__ __launch_bounds__(256) void bn_fused(const unsigned short* __restrict__ feat,
                                                const float* __restrict__ lin_w,
                                                const float* __restrict__ lin_b,
                                                const float* __restrict__ gam,
                                                const float* __restrict__ bet,
                                                float* __restrict__ stats,
                                                unsigned* __restrict__ bnbar,
                                                float* __restrict__ x) {
    __shared__ float wls[KF * C];
    __shared__ float red[4][2][C];
    __shared__ float st[2 * C];
    int t = threadIdx.x;
    wls[t] = lin_w[t];
    __syncthreads();
    int b = blockIdx.x & 7, sub = blockIdx.x >> 3;   // sub 0..31
    const uint2* fb = (const uint2*)(feat + (size_t)b * KF * NM);

    // ---- phase 1: stats partials (4 quad-chunks per thread) ----
    float s[C] = {}, ss[C] = {};
    #pragma unroll
    for (int chunk = 0; chunk < 4; chunk++) {
        int i = sub * 1024 + chunk * 256 + t;        // quad index within batch
        float4 hq[C];
        #pragma unroll
        for (int c = 0; c < C; c++) {
            float bb = lin_b[c];
            hq[c] = make_float4(bb, bb, bb, bb);
        }
        for (int kk = 0; kk < KF; kk++) {
            U2 u; u.v = fb[(size_t)kk * (NM / 4) + i];
            float p0 = bf2f(u.s[0]), p1 = bf2f(u.s[1]), p2 = bf2f(u.s[2]), p3 = bf2f(u.s[3]);
            #pragma unroll
            for (int c = 0; c < C; c++) {
                float wv = wls[kk * C + c];
                hq[c].x = fmaf(p0, wv, hq[c].x);
                hq[c].y = fmaf(p1, wv, hq[c].y);
                hq[c].z = fmaf(p2, wv, hq[c].z);
                hq[c].w = fmaf(p3, wv, hq[c].w);
            }
        }
        #pragma unroll
        for (int c = 0; c < C; c++) {
            float4 h = hq[c];
            s[c] += h.x + h.y + h.z + h.w;
            ss[c] += h.x * h.x + h.y * h.y + h.z * h.z + h.w * h.w;
        }
    }
    #pragma unroll
    for (int off = 32; off > 0; off >>= 1)
        #pragma unroll
        for (int c = 0; c < C; c++) {
            s[c] += __shfl_down(s[c], off);
            ss[c] += __shfl_down(ss[c], off);
        }
    if ((t & 63) == 0) {
        int wv = t >> 6;
        #pragma unroll
        for (int c = 0; c < C; c++) { red[wv][0][c] = s[c]; red[wv][1][c] = ss[c]; }
    }
    __syncthreads();
    if (t < 32) {
        int which = t >> 4, c = t & 15;
        float v = red[0][which][c] + red[1][which][c] + red[2][which][c] + red[3][which][c];
        atomicAdd(&stats[b * 32 + which * 16 + c], v);
    }
    // ---- per-batch barrier (32 blocks, same XCD) ----
    __syncthreads();
    if (t == 0) {
        __hip_atomic_fetch_add(&bnbar[b * 32], 1u, __ATOMIC_RELAXED, __HIP_MEMORY_SCOPE_AGENT);
        while (__hip_atomic_load(&bnbar[b * 32], __ATOMIC_RELAXED, __HIP_MEMORY_SCOPE_AGENT) < 32u)
            __builtin_amdgcn_s_sleep(1);
    }
    __syncthreads();
    if (t < 32) {
        float* sp = &stats[b * 32 + t];
        st[t] = __hip_atomic_load(sp, __ATOMIC_RELAXED, __HIP_MEMORY_SCOPE_AGENT);
    }
    __syncthreads();

    // ---- phase 2: BN apply + relu + mean over M -> x (vectorized, L2-warm) ----
    const float inv_nm = 1.0f / (float)NM;
    float sc[C], sh[C], bb2[C];
    #pragma unroll
    for (int c = 0; c < C; c++) {
        float mean = st[c] * inv_nm;
        float var = st[16 + c] * inv_nm - mean * mean;
        sc[c] = gam[c] * rsqrtf(var + BN_EPS);
        sh[c] = bet[c] - mean * sc[c];
        bb2[c] = lin_b[c];
    }
    int n0 = sub * 32;
    int nl = t >> 3, mlane = t & 7;                  // 32 nodes x 8 lanes
    int n = n0 + nl;
    const unsigned short* fn = feat + (size_t)b * KF * NM + (size_t)n * M;
    float y[C] = {};
    #pragma unroll
    for (int chunk = 0; chunk < 4; chunk++) {
        int m0 = mlane * 4 + chunk * 32;
        float4 hq[C];
        #pragma unroll
        for (int c = 0; c < C; c++) {
            float bb = bb2[c];
            hq[c] = make_float4(bb, bb, bb, bb);
        }
        for (int kk = 0; kk < KF; kk++) {
            U2 u; u.v = *(const uint2*)(fn + (size_t)kk * NM + m0);
            float p0 = bf2f(u.s[0]), p1 = bf2f(u.s[1]), p2 = bf2f(u.s[2]), p3 = bf2f(u.s[3]);
            #pragma unroll
            for (int c = 0; c < C; c++) {
                float wv = wls[kk * C + c];
                hq[c].x = fmaf(p0, wv, hq[c].x);
                hq[c].y = fmaf(p1, wv, hq[c].y);
                hq[c].z = fmaf(p2, wv, hq[c].z);
                hq[c].w = fmaf(p3, wv, hq[c].w);
            }
        }
        #pragma unroll
        for (int c = 0; c < C; c++) {
            float4 h = hq[c];
            y[c] += fmaxf(fmaf(h.x, sc[c], sh[c]), 0.0f);
            y[c] += fmaxf(fmaf(h.y, sc[c], sh[c]), 0.0f);
            y[c] += fmaxf(fmaf(h.z, sc[c], sh[c]), 0.0f);
            y[c] += fmaxf(fmaf(h.w, sc[c], sh[c]), 0.0f);
        }
    }
    #pragma unroll
    for (int off = 4; off > 0; off >>= 1)
        #pragma unroll
        for (int c = 0; c < C; c++) y[c] += __shfl_down(y[c], off);
    if (mlane == 0) {
        #pragma unroll
        for (int c = 0; c < C; c++)
            x[((size_t)b * N + n) * C + c] = y[c] * (1.0f / (float)M);
    }
}

// ---------- single-kernel edge CSR: hist -> grid barrier -> scan -> fill ----------
// 512 blocks x 256 thr (2/CU, tiny VGPR -> co-resident). Cross-XCD data via
// device atomics only (hist adds, scan atomic loads/stores, fill atomicAdd).
__global__ __launch_bounds__(256) void edge_build(const int* __restrict__ ei,
                                                  int* __restrict__ cnt,
                                                  int* __restrict__ off,
                                                  int* __restrict__ cur,
                                                  int* __restrict__ bucket,
                                                  unsigned* __restrict__ ebar) {
    __shared__ int sscan[256];
    int t = threadIdx.x;
    int e = blockIdx.x * 256 + t;
    bool is64 = (ei[1] == 0 && ei[3] == 0 && ei[5] == 0 && ei[7] == 0);
    int src, dst;
    if (is64) { src = ei[2 * e]; dst = ei[2 * (NE + e)]; }
    else      { src = ei[e];     dst = ei[NE + e]; }
    atomicAdd(&cnt[dst], 1);
    __syncthreads();                               // drain atomics (vmcnt 0)
    if (t == 0) {
        __hip_atomic_fetch_add(&ebar[0], 1u, __ATOMIC_RELAXED, __HIP_MEMORY_SCOPE_AGENT);
        while (__hip_atomic_load(&ebar[0], __ATOMIC_RELAXED, __HIP_MEMORY_SCOPE_AGENT) < 512u)
            __builtin_amdgcn_s_sleep(1);
    }
    __syncthreads();
    if (blockIdx.x == 0) {                         // scan by block 0
        int base = t * 32;
        int local[32];
        int s = 0;
        #pragma unroll
        for (int i = 0; i < 32; i++) {
            local[i] = __hip_atomic_load(&cnt[base + i], __ATOMIC_RELAXED, __HIP_MEMORY_SCOPE_AGENT);
            s += local[i];
        }
        sscan[t] = s;
        __syncthreads();
        #pragma unroll
        for (int d = 1; d < 256; d <<= 1) {
            int v = (t >= d) ? sscan[t - d] : 0;
            __syncthreads();
            sscan[t] += v;
            __syncthreads();
        }
        int excl = sscan[t] - s;
        #pragma unroll
        for (int i = 0; i < 32; i++) {
            __hip_atomic_store(&off[base + i], excl, __ATOMIC_RELAXED, __HIP_MEMORY_SCOPE_AGENT);
            __hip_atomic_store(&cur[base + i], excl, __ATOMIC_RELAXED, __HIP_MEMORY_SCOPE_AGENT);
            excl += local[i];
        }
        __syncthreads();
        if (t == 0)
            __hip_atomic_store(&ebar[64], 1u, __ATOMIC_RELAXED, __HIP_MEMORY_SCOPE_AGENT);
    }
    if (t == 0) {
        while (__hip_atomic_load(&ebar[64], __ATOMIC_RELAXED, __HIP_MEMORY_SCOPE_AGENT) == 0u)
            __builtin_amdgcn_s_sleep(1);
    }
    __syncthreads();
    int pos = atomicAdd(&cur[dst], 1);
    bucket[pos] = src;                             // plain store; read next dispatch
}

// ---------- fused gather + phi1 + phi2 ----------
__global__ __launch_bounds__(256) void phi_fused(const int* __restrict__ cnt,
                                                 const int* __restrict__ off,
                                                 const int* __restrict__ bucket,
                                                 const float* __restrict__ x,
                                                 const float* __restrict__ w1,
                                                 const float* __restrict__ b1,
                                                 const float* __restrict__ w2,
                                                 const float* __restrict__ b2,
                                                 float* __restrict__ out) {
    __shared__ float w1s[C * DPE];
    __shared__ float w2s[DPE * DPE];
    __shared__ float b2s[DPE];
    __shared__ float gsh[16][17];
    __shared__ float h1sh[16][DPE];
    int t = threadIdx.x;
    #pragma unroll
    for (int q = 0; q < 4; q++) w1s[t + q * 256] = w1[t + q * 256];
    #pragma unroll
    for (int q = 0; q < 16; q++) w2s[t + q * 256] = w2[t + q * 256];
    if (t < DPE) b2s[t] = b2[t];

    {   // gather: node nl, channel c
        int nl = t >> 4, c = t & 15;
        int n = blockIdx.x * 16 + nl;
        int o = off[n], d = cnt[n];
        float v = x[(size_t)n * C + c];
        int j = 0;
        for (; j + 4 <= d; j += 4) {
            int s0 = bucket[o + j], s1 = bucket[o + j + 1];
            int s2 = bucket[o + j + 2], s3 = bucket[o + j + 3];
            v += x[(size_t)s0 * C + c];
            v += x[(size_t)s1 * C + c];
            v += x[(size_t)s2 * C + c];
            v += x[(size_t)s3 * C + c];
        }
        for (; j < d; j++) v += x[(size_t)bucket[o + j] * C + c];
        gsh[nl][c] = v;
    }
    __syncthreads();
    #pragma unroll
    for (int q = 0; q < 4; q++) {
        int item = t + 256 * q;
        int node = item >> 6, j = item & 63;
        float h = b1[j];
        #pragma unroll
        for (int c = 0; c < C; c++) h = fmaf(gsh[node][c], w1s[c * DPE + j], h);
        h1sh[node][j] = fmaxf(h, 0.0f);
    }
    __syncthreads();
    #pragma unroll
    for (int q = 0; q < 4; q++) {
        int item = t + 256 * q;
        int node = item >> 6, d = item & 63;
        float o2 = b2s[d];
        #pragma unroll
        for (int j = 0; j < DPE; j++) o2 = fmaf(h1sh[node][j], w2s[j * DPE + d], o2);
        out[((size_t)blockIdx.x * 16 + node) * DPE + d] = o2;
    }
}

extern "C" void kernel_launch(void* const* d_in, const int* in_sizes, int n_in,
                              void* d_out, int out_size, void* d_ws, size_t ws_size,
                              hipStream_t stream) {
    const float* Lap   = (const float*)d_in[0];
    const float* W     = (const float*)d_in[1];
    const float* lin_w = (const float*)d_in[2];
    const float* lin_b = (const float*)d_in[3];
    const float* gam   = (const float*)d_in[4];
    const float* bet   = (const float*)d_in[5];
    const float* w1    = (const float*)d_in[6];
    const float* b1    = (const float*)d_in[7];
    const float* w2    = (const float*)d_in[8];
    const float* b2    = (const float*)d_in[9];
    const int*   ei    = (const int*)d_in[10];

    char* wsb = (char*)d_ws;
    unsigned short* feat = (unsigned short*)wsb;             // 32 MB (bf16, [node][m])
    uint4* Sf    = (uint4*)(wsb + ((size_t)32 << 20));       // 32 MB
    uint4* Pf    = (uint4*)(wsb + ((size_t)64 << 20));       // 8 MB (2 buffers)
    float* stats = (float*)(wsb + ((size_t)72 << 20));       // zeroed 8KB region:
    unsigned* bar   = (unsigned*)((char*)stats + 1024);      //   chain barrier
    unsigned* bnbar = (unsigned*)((char*)stats + 2048);      //   bn barrier
    unsigned* ebar  = (unsigned*)((char*)stats + 4096);      //   edge barriers
    float* x     = stats + 2048;                             // byte offset 8192
    int*   cnt   = (int*)(x + (size_t)NV * C);
    int*   off   = cnt + NV;
    int*   cur   = off + NV;
    int*   bucket= cur + NV;                                 // NE ints
    float* out   = (float*)d_out;

    static bool attr_set = false;
    if (!attr_set) {
        hipFuncSetAttribute((const void*)gemm_chain,
                            hipFuncAttributeMaxDynamicSharedMemorySize, 149504);
        attr_set = true;
    }

    hipMemsetAsync(stats, 0, 8192, stream);                  // stats + all barriers
    hipMemsetAsync(cnt, 0, NV * sizeof(int), stream);
    prep_all<<<dim3(2048), 256, 0, stream>>>(Lap, W, Sf, Pf, feat);
    gemm_chain<<<dim3(256), 512, 149504, stream>>>(Sf, Pf, Pf + PFBUF, feat, bar);
    bn_fused<<<dim3(256), 256, 0, stream>>>(feat, lin_w, lin_b, gam, bet, stats, bnbar, x);
    edge_build<<<dim3(512), 256, 0, stream>>>(ei, cnt, off, cur, bucket, ebar);
    phi_fused<<<dim3(NV / 16), 256, 0, stream>>>(cnt, off, bucket, x, w1, b1, w2, b2, out);
}